// Round 1
// baseline (596.106 us; speedup 1.0000x reference)
//
#include <hip/hip_runtime.h>
#include <stdint.h>

#define EPSF 1e-6f

typedef unsigned short u16;
typedef __attribute__((ext_vector_type(8))) short short8;
typedef __attribute__((ext_vector_type(4))) float f32x4;

__device__ __forceinline__ float us2f(u16 u) {
  union { float f; unsigned int i; } c; c.i = ((unsigned int)u) << 16; return c.f;
}
__device__ __forceinline__ u16 f2bfu(float f) {
  union { float f; unsigned int i; } c; c.f = f;
  unsigned int i = c.i;
  return (u16)((i + 0x7FFFu + ((i >> 16) & 1u)) >> 16);
}
__device__ __forceinline__ float sigm(float x) { return 1.f / (1.f + __expf(-x)); }

typedef __attribute__((address_space(3))) unsigned int lds_u32;
typedef const __attribute__((address_space(1))) unsigned int glb_u32;
__device__ __forceinline__ void gl_lds16(const u16* g, u16* l) {
  __builtin_amdgcn_global_load_lds((glb_u32*)g, (lds_u32*)l, 16, 0, 0);
}

// ---------------- convert x (f32 -> bf16), 4 elems/thread ----------------
__global__ void k_cvt_x(const float* __restrict__ in, u16* __restrict__ out) {
  const int i = blockIdx.x * 256 + threadIdx.x;
  float4 v = ((const float4*)in)[i];
  ushort4 o;
  o.x = f2bfu(v.x); o.y = f2bfu(v.y); o.z = f2bfu(v.z); o.w = f2bfu(v.w);
  ((ushort4*)out)[i] = o;
}

// ---------------- transpose + convert: in f32 [R][C] -> out bf16 [C][R] ----------------
__global__ void k_transpose(const float* __restrict__ in, u16* __restrict__ out, int R, int C) {
  __shared__ float tile[32][33];
  const int tx = threadIdx.x & 31, ty = threadIdx.x >> 5;  // 32x8
  const int c0 = blockIdx.x << 5, r0 = blockIdx.y << 5;
  for (int i = ty; i < 32; i += 8) tile[i][tx] = in[(size_t)(r0 + i) * C + c0 + tx];
  __syncthreads();
  for (int i = ty; i < 32; i += 8) out[(size_t)(c0 + i) * R + r0 + tx] = f2bfu(tile[tx][i]);
}

// ---------------- GEMM: A[M][768] bf16 x BT[NC][768] bf16, 128x128 tile, BK=32 ----------------
// MODE 0: qkv epilogue (bias + sigmoid q/k, scatter to [B,H,N,D]); MODE 1: proj epilogue.
template <int MODE>
__global__ __launch_bounds__(256) void k_gemm(
    const u16* __restrict__ A, const u16* __restrict__ BT,
    const float* __restrict__ bias,
    u16* __restrict__ qo, u16* __restrict__ ko, u16* __restrict__ vo,
    float* __restrict__ outf)
{
  __shared__ __align__(16) u16 sA[2][128 * 32];
  __shared__ __align__(16) u16 sB[2][128 * 32];
  const int tid = threadIdx.x;
  const int lane = tid & 63;
  const int wid = tid >> 6;
  const int wr = wid >> 1, wc = wid & 1;
  const int m0 = blockIdx.y << 7;
  const int n0 = blockIdx.x << 7;
  const int srow = lane >> 2;          // 0..15 (row within 16-row chunk)
  const int skb = (lane & 3) << 3;     // 0,8,16,24 (k elems)

  const u16* ga0 = A  + (size_t)(m0 + (wid << 4) + srow) * 768 + skb;
  const u16* ga1 = A  + (size_t)(m0 + ((wid + 4) << 4) + srow) * 768 + skb;
  const u16* gb0 = BT + (size_t)(n0 + (wid << 4) + srow) * 768 + skb;
  const u16* gb1 = BT + (size_t)(n0 + ((wid + 4) << 4) + srow) * 768 + skb;

  f32x4 acc[4][4];
#pragma unroll
  for (int i = 0; i < 4; ++i)
#pragma unroll
    for (int j = 0; j < 4; ++j) acc[i][j] = (f32x4){0.f, 0.f, 0.f, 0.f};

#define STAGE(buf, ktel)                                        \
  do {                                                          \
    gl_lds16(ga0 + (ktel), &sA[buf][(wid) * 512]);              \
    gl_lds16(ga1 + (ktel), &sA[buf][(wid + 4) * 512]);          \
    gl_lds16(gb0 + (ktel), &sB[buf][(wid) * 512]);              \
    gl_lds16(gb1 + (ktel), &sB[buf][(wid + 4) * 512]);          \
  } while (0)

  STAGE(0, 0);
  asm volatile("s_waitcnt vmcnt(0)" ::: "memory");
  __syncthreads();

  const int r16 = lane & 15;
  const int kg8 = (lane >> 4) << 3;
  int cur = 0;
  for (int kt = 1; kt <= 24; ++kt) {
    if (kt < 24) {
      if (cur) STAGE(0, kt * 32); else STAGE(1, kt * 32);
    }
    const u16* pa = &sA[cur][0];
    const u16* pb = &sB[cur][0];
    short8 af[4], bfv[4];
#pragma unroll
    for (int i = 0; i < 4; ++i)
      af[i] = *(const short8*)(pa + ((wr << 6) + (i << 4) + r16) * 32 + kg8);
#pragma unroll
    for (int j = 0; j < 4; ++j)
      bfv[j] = *(const short8*)(pb + ((wc << 6) + (j << 4) + r16) * 32 + kg8);
#pragma unroll
    for (int i = 0; i < 4; ++i)
#pragma unroll
      for (int j = 0; j < 4; ++j)
        acc[i][j] = __builtin_amdgcn_mfma_f32_16x16x32_bf16(af[i], bfv[j], acc[i][j], 0, 0, 0);
    asm volatile("s_waitcnt vmcnt(0)" ::: "memory");
    __syncthreads();
    cur ^= 1;
  }
#undef STAGE

#pragma unroll
  for (int i = 0; i < 4; ++i) {
    const int rowb = m0 + (wr << 6) + (i << 4) + ((lane >> 4) << 2);
#pragma unroll
    for (int j = 0; j < 4; ++j) {
      const int col = n0 + (wc << 6) + (j << 4) + r16;
      const float bcol = bias[col];
      if (MODE == 0) {
        const int s = (col >= 1536) ? 2 : ((col >= 768) ? 1 : 0);
        const int cr = col - s * 768;
        const int h = cr >> 6, d = cr & 63;
        u16* dst = (s == 0) ? qo : ((s == 1) ? ko : vo);
#pragma unroll
        for (int rg = 0; rg < 4; ++rg) {
          const int row = rowb + rg;
          const int b = row >> 12, n = row & 4095;
          float val = acc[i][j][rg] + bcol;
          if (s < 2) val = sigm(val);
          dst[(((size_t)(b * 12 + h) << 12) + n) * 64 + d] = f2bfu(val);
        }
      } else {
#pragma unroll
        for (int rg = 0; rg < 4; ++rg) {
          const int row = rowb + rg;
          outf[(size_t)row * 768 + col] = sigm(2.f * (acc[i][j][rg] + bcol));
        }
      }
    }
  }
}

// ---------------- qsum/ksum over N (atomics across 8 n-splits) ----------------
__global__ __launch_bounds__(256) void k_sums(const u16* __restrict__ q, const u16* __restrict__ k,
                                              float* __restrict__ qsum, float* __restrict__ ksum) {
  const int bh = blockIdx.x >> 3, sp = blockIdx.x & 7;
  const int d = threadIdx.x & 63, sub = threadIdx.x >> 6;
  const u16* qb = q + ((size_t)bh << 18);
  const u16* kb = k + ((size_t)bh << 18);
  const int nlo = (sp << 9) + (sub << 7);
  float sq = 0.f, sk = 0.f;
  for (int n = nlo; n < nlo + 128; ++n) {
    sq += us2f(qb[((size_t)n << 6) + d]);
    sk += us2f(kb[((size_t)n << 6) + d]);
  }
  __shared__ float rq[4][64], rk[4][64];
  rq[sub][d] = sq; rk[sub][d] = sk;
  __syncthreads();
  if (threadIdx.x < 64) {
    atomicAdd(&qsum[(bh << 6) + d], rq[0][d] + rq[1][d] + rq[2][d] + rq[3][d]);
  } else if (threadIdx.x < 128) {
    const int dd = threadIdx.x - 64;
    atomicAdd(&ksum[(bh << 6) + dd], rk[0][dd] + rk[1][dd] + rk[2][dd] + rk[3][dd]);
  }
}

// ---------------- si/so + qsi/kso (quarter-wave owns one n; lane j owns 4 d's) ----------------
__global__ __launch_bounds__(256) void k_flow1(
    const u16* __restrict__ q, const u16* __restrict__ k,
    const float* __restrict__ qsum, const float* __restrict__ ksum,
    float* __restrict__ si_out, float* __restrict__ qsi, float* __restrict__ kso)
{
  const int bh = blockIdx.x >> 3, sp = blockIdx.x & 7;
  const int lane = threadIdx.x & 63, wid = threadIdx.x >> 6;
  const int j = lane & 15;
  const int grp = (wid << 2) | (lane >> 4);
  const u16* qb = q + ((size_t)bh << 18);
  const u16* kb = k + ((size_t)bh << 18);
  float ke[4], qe[4];
#pragma unroll
  for (int t = 0; t < 4; ++t) {
    ke[t] = ksum[(bh << 6) + (j << 2) + t] + EPSF;
    qe[t] = qsum[(bh << 6) + (j << 2) + t] + EPSF;
  }
  float Sk = ke[0] + ke[1] + ke[2] + ke[3];
  float Sq = qe[0] + qe[1] + qe[2] + qe[3];
#pragma unroll
  for (int msk = 1; msk < 16; msk <<= 1) { Sk += __shfl_xor(Sk, msk, 64); Sq += __shfl_xor(Sq, msk, 64); }
  const float cK = EPSF * Sk + EPSF;
  const float cQ = EPSF * Sq + EPSF;
  float aq0 = 0, aq1 = 0, aq2 = 0, aq3 = 0, ak0 = 0, ak1 = 0, ak2 = 0, ak3 = 0;
  const int nbase = sp << 9;
  for (int it = 0; it < 32; ++it) {
    const int n = nbase + (it << 4) + grp;
    const uint64_t lq = *(const uint64_t*)(qb + ((size_t)n << 6) + (j << 2));
    const uint64_t lk = *(const uint64_t*)(kb + ((size_t)n << 6) + (j << 2));
    const float q0 = us2f((u16)lq), q1 = us2f((u16)(lq >> 16)), q2 = us2f((u16)(lq >> 32)), q3 = us2f((u16)(lq >> 48));
    const float k0 = us2f((u16)lk), k1 = us2f((u16)(lk >> 16)), k2 = us2f((u16)(lk >> 32)), k3 = us2f((u16)(lk >> 48));
    float dq = q0 * ke[0] + q1 * ke[1] + q2 * ke[2] + q3 * ke[3];
    float dk = k0 * qe[0] + k1 * qe[1] + k2 * qe[2] + k3 * qe[3];
#pragma unroll
    for (int msk = 1; msk < 16; msk <<= 1) { dq += __shfl_xor(dq, msk, 64); dk += __shfl_xor(dk, msk, 64); }
    const float si = 1.f / (dq + cK);
    const float so = 1.f / (dk + cQ);
    if (j == 0) si_out[(bh << 12) + n] = si;
    aq0 += q0 * si; aq1 += q1 * si; aq2 += q2 * si; aq3 += q3 * si;
    ak0 += k0 * so; ak1 += k1 * so; ak2 += k2 * so; ak3 += k3 * so;
  }
  __shared__ float redq[16][64];
  __shared__ float redk[16][64];
  redq[grp][(j << 2) + 0] = aq0; redq[grp][(j << 2) + 1] = aq1;
  redq[grp][(j << 2) + 2] = aq2; redq[grp][(j << 2) + 3] = aq3;
  redk[grp][(j << 2) + 0] = ak0; redk[grp][(j << 2) + 1] = ak1;
  redk[grp][(j << 2) + 2] = ak2; redk[grp][(j << 2) + 3] = ak3;
  __syncthreads();
  if (threadIdx.x < 64) {
    float s1 = 0.f, s2 = 0.f;
#pragma unroll
    for (int g = 0; g < 16; ++g) { s1 += redq[g][threadIdx.x]; s2 += redk[g][threadIdx.x]; }
    atomicAdd(&qsi[(bh << 6) + threadIdx.x], s1);
    atomicAdd(&kso[(bh << 6) + threadIdx.x], s2);
  }
}

// ---------------- conserved sink/source -> m = si*sigmoid(cs); e = exp(clip(csrc)); sumexp ----------------
__global__ __launch_bounds__(256) void k_flow2(
    const u16* __restrict__ q, const u16* __restrict__ k,
    const float* __restrict__ qsi, const float* __restrict__ kso,
    const float* __restrict__ si_in,
    float* __restrict__ mo, float* __restrict__ eo, float* __restrict__ sumexp)
{
  const int bh = blockIdx.x >> 3, sp = blockIdx.x & 7;
  const int lane = threadIdx.x & 63, wid = threadIdx.x >> 6;
  const int j = lane & 15;
  const int grp = (wid << 2) | (lane >> 4);
  const u16* qb = q + ((size_t)bh << 18);
  const u16* kb = k + ((size_t)bh << 18);
  float soe[4], qie[4];
#pragma unroll
  for (int t = 0; t < 4; ++t) {
    soe[t] = kso[(bh << 6) + (j << 2) + t] + EPSF;
    qie[t] = qsi[(bh << 6) + (j << 2) + t] + EPSF;
  }
  float Ss = soe[0] + soe[1] + soe[2] + soe[3];
  float Si = qie[0] + qie[1] + qie[2] + qie[3];
#pragma unroll
  for (int msk = 1; msk < 16; msk <<= 1) { Ss += __shfl_xor(Ss, msk, 64); Si += __shfl_xor(Si, msk, 64); }
  const float cS = EPSF * Ss + EPSF;
  const float cR = EPSF * Si + EPSF;
  float esum = 0.f;
  const int nbase = sp << 9;
  for (int it = 0; it < 32; ++it) {
    const int n = nbase + (it << 4) + grp;
    const uint64_t lq = *(const uint64_t*)(qb + ((size_t)n << 6) + (j << 2));
    const uint64_t lk = *(const uint64_t*)(kb + ((size_t)n << 6) + (j << 2));
    const float q0 = us2f((u16)lq), q1 = us2f((u16)(lq >> 16)), q2 = us2f((u16)(lq >> 32)), q3 = us2f((u16)(lq >> 48));
    const float k0 = us2f((u16)lk), k1 = us2f((u16)(lk >> 16)), k2 = us2f((u16)(lk >> 32)), k3 = us2f((u16)(lk >> 48));
    float cs = q0 * soe[0] + q1 * soe[1] + q2 * soe[2] + q3 * soe[3];
    float cr = k0 * qie[0] + k1 * qie[1] + k2 * qie[2] + k3 * qie[3];
#pragma unroll
    for (int msk = 1; msk < 16; msk <<= 1) { cs += __shfl_xor(cs, msk, 64); cr += __shfl_xor(cr, msk, 64); }
    cs += cS;
    cr += cR;
    cr = fminf(1.f, fmaxf(-1.f, cr));
    const float ev = __expf(cr);
    if (j == 0) {
      const float sa = sigm(cs);
      mo[(bh << 12) + n] = si_in[(bh << 12) + n] * sa;
      eo[(bh << 12) + n] = ev;
      esum += ev;
    }
  }
  __shared__ float red[16];
  if (j == 0) red[grp] = esum;
  __syncthreads();
  if (threadIdx.x == 0) {
    float s = 0.f;
#pragma unroll
    for (int g = 0; g < 16; ++g) s += red[g];
    atomicAdd(&sumexp[bh], s);
  }
}

// ---------------- kvT[e][d] = sum_n k[n,d] * v[n,e] * e[n]  (4 n-splits, atomics) ----------------
__global__ __launch_bounds__(256) void k_kv(
    const u16* __restrict__ k, const u16* __restrict__ v,
    const float* __restrict__ e_arr, float* __restrict__ kvT)
{
  const int bh = blockIdx.x >> 2, sp = blockIdx.x & 3;
  const int d4 = (threadIdx.x & 15) << 2;
  const int e4 = (threadIdx.x >> 4) << 2;
  const u16* kb = k + ((size_t)bh << 18);
  const u16* vb = v + ((size_t)bh << 18);
  const float* eb = e_arr + ((size_t)bh << 12);
  float acc[4][4];
#pragma unroll
  for (int a = 0; a < 4; ++a)
#pragma unroll
    for (int b = 0; b < 4; ++b) acc[a][b] = 0.f;
  const int nlo = sp << 10;
#pragma unroll 2
  for (int n = nlo; n < nlo + 1024; ++n) {
    const float en = eb[n];
    const uint64_t lk = *(const uint64_t*)(kb + ((size_t)n << 6) + d4);
    const uint64_t lv = *(const uint64_t*)(vb + ((size_t)n << 6) + e4);
    const float kk0 = us2f((u16)lk), kk1 = us2f((u16)(lk >> 16)), kk2 = us2f((u16)(lk >> 32)), kk3 = us2f((u16)(lk >> 48));
    float vv0 = us2f((u16)lv) * en, vv1 = us2f((u16)(lv >> 16)) * en, vv2 = us2f((u16)(lv >> 32)) * en, vv3 = us2f((u16)(lv >> 48)) * en;
    acc[0][0] += vv0 * kk0; acc[0][1] += vv0 * kk1; acc[0][2] += vv0 * kk2; acc[0][3] += vv0 * kk3;
    acc[1][0] += vv1 * kk0; acc[1][1] += vv1 * kk1; acc[1][2] += vv1 * kk2; acc[1][3] += vv1 * kk3;
    acc[2][0] += vv2 * kk0; acc[2][1] += vv2 * kk1; acc[2][2] += vv2 * kk2; acc[2][3] += vv2 * kk3;
    acc[3][0] += vv3 * kk0; acc[3][1] += vv3 * kk1; acc[3][2] += vv3 * kk2; acc[3][3] += vv3 * kk3;
  }
#pragma unroll
  for (int a = 0; a < 4; ++a)
#pragma unroll
    for (int b = 0; b < 4; ++b)
      atomicAdd(&kvT[((size_t)bh << 12) + ((size_t)(e4 + a) << 6) + d4 + b], acc[a][b]);
}

// ---------------- x_update = (q @ kv) * m[n] * scale -> attn [B][N][C] bf16 (MFMA) ----------------
__global__ __launch_bounds__(256) void k_xup(
    const u16* __restrict__ q, const float* __restrict__ kvT,
    const float* __restrict__ m_arr, const float* __restrict__ sumexp,
    u16* __restrict__ attn)
{
  const int bh = blockIdx.y;
  const int n0 = blockIdx.x << 7;
  const int b = bh / 12, h = bh % 12;
  __shared__ __align__(16) u16 qs[128 * 64];
  __shared__ __align__(16) u16 kvs[64 * 64];
  const int tid = threadIdx.x, lane = tid & 63, wid = tid >> 6;
  const u16* qg = q + ((size_t)bh << 18) + ((size_t)n0 << 6);
#pragma unroll
  for (int cc = 0; cc < 4; ++cc) {
    const int c = (wid << 2) + cc;
    gl_lds16(qg + (c << 9) + (lane << 3), &qs[c << 9]);
  }
  const float* kvg = kvT + ((size_t)bh << 12);
#pragma unroll
  for (int i = 0; i < 4; ++i) {
    const int idx = ((i << 8) + tid) << 2;
    float4 vv = *(const float4*)(kvg + idx);
    ushort4 o;
    o.x = f2bfu(vv.x); o.y = f2bfu(vv.y); o.z = f2bfu(vv.z); o.w = f2bfu(vv.w);
    *(ushort4*)&kvs[idx] = o;
  }
  asm volatile("s_waitcnt vmcnt(0)" ::: "memory");
  __syncthreads();
  const float scale = 4096.f / sumexp[bh];
  const int r16 = lane & 15, kg8 = (lane >> 4) << 3;
  f32x4 acc[2][4];
#pragma unroll
  for (int i = 0; i < 2; ++i)
#pragma unroll
    for (int j = 0; j < 4; ++j) acc[i][j] = (f32x4){0.f, 0.f, 0.f, 0.f};
#pragma unroll
  for (int kk = 0; kk < 2; ++kk) {
    short8 af[2], bfv[4];
#pragma unroll
    for (int mi = 0; mi < 2; ++mi)
      af[mi] = *(const short8*)&qs[((wid << 5) + (mi << 4) + r16) * 64 + (kk << 5) + kg8];
#pragma unroll
    for (int nj = 0; nj < 4; ++nj)
      bfv[nj] = *(const short8*)&kvs[((nj << 4) + r16) * 64 + (kk << 5) + kg8];
#pragma unroll
    for (int mi = 0; mi < 2; ++mi)
#pragma unroll
      for (int nj = 0; nj < 4; ++nj)
        acc[mi][nj] = __builtin_amdgcn_mfma_f32_16x16x32_bf16(af[mi], bfv[nj], acc[mi][nj], 0, 0, 0);
  }
#pragma unroll
  for (int mi = 0; mi < 2; ++mi) {
#pragma unroll
    for (int rg = 0; rg < 4; ++rg) {
      const int n = n0 + (wid << 5) + (mi << 4) + ((lane >> 4) << 2) + rg;
      const float mult = m_arr[((size_t)bh << 12) + n] * scale;
#pragma unroll
      for (int nj = 0; nj < 4; ++nj) {
        const int e = (nj << 4) + r16;
        attn[((size_t)(b * 4096 + n)) * 768 + (h << 6) + e] = f2bfu(acc[mi][nj][rg] * mult);
      }
    }
  }
}

extern "C" void kernel_launch(void* const* d_in, const int* in_sizes, int n_in,
                              void* d_out, int out_size, void* d_ws, size_t ws_size,
                              hipStream_t stream)
{
  (void)in_sizes; (void)n_in; (void)out_size; (void)ws_size;
  const float* x     = (const float*)d_in[0];
  const float* Wqkv  = (const float*)d_in[1];
  const float* bqkv  = (const float*)d_in[2];
  const float* Wproj = (const float*)d_in[3];
  const float* bproj = (const float*)d_in[4];
  float* out = (float*)d_out;

  char* ws = (char*)d_ws;
  size_t off = 0;
  auto alloc = [&](size_t bytes) -> char* {
    char* p = ws + off;
    off += (bytes + 255) & ~(size_t)255;
    return p;
  };
  u16* q    = (u16*)alloc(50331648);       // [B,H,N,D] bf16
  u16* k    = (u16*)alloc(50331648);
  u16* v    = (u16*)alloc(50331648);
  u16* xbf  = (u16*)alloc(50331648);       // x bf16; reused as attn output
  u16* WqT  = (u16*)alloc(3538944);        // [2304][768] bf16
  u16* WpT  = (u16*)alloc(1179648);        // [768][768] bf16
  float* si = (float*)alloc(1572864);      // [B*H][N]
  float* mb = (float*)alloc(1572864);      // si * sink_allocation
  float* eb = (float*)alloc(1572864);      // exp(clipped conserved_source)
  char* zbase = ws + off;
  float* qsum   = (float*)alloc(24576);
  float* ksum   = (float*)alloc(24576);
  float* qsi    = (float*)alloc(24576);
  float* kso    = (float*)alloc(24576);
  float* sumexp = (float*)alloc(512);
  float* kvT    = (float*)alloc(1572864);  // [B*H][64 e][64 d]
  const size_t zbytes = (size_t)((ws + off) - zbase);

  hipMemsetAsync(zbase, 0, zbytes, stream);
  k_cvt_x<<<24576, 256, 0, stream>>>(x, xbf);
  k_transpose<<<dim3(72, 24), 256, 0, stream>>>(Wqkv, WqT, 768, 2304);
  k_transpose<<<dim3(24, 24), 256, 0, stream>>>(Wproj, WpT, 768, 768);
  k_gemm<0><<<dim3(18, 256), 256, 0, stream>>>(xbf, WqT, bqkv, q, k, v, nullptr);
  k_sums<<<768, 256, 0, stream>>>(q, k, qsum, ksum);
  k_flow1<<<768, 256, 0, stream>>>(q, k, qsum, ksum, si, qsi, kso);
  k_flow2<<<768, 256, 0, stream>>>(q, k, qsi, kso, si, mb, eb, sumexp);
  k_kv<<<384, 256, 0, stream>>>(k, v, eb, kvT);
  k_xup<<<dim3(32, 96), 256, 0, stream>>>(q, kvT, mb, sumexp, xbf);
  k_gemm<1><<<dim3(6, 256), 256, 0, stream>>>(xbf, WpT, bproj, nullptr, nullptr, nullptr, out);
}

// Round 3
// 477.152 us; speedup vs baseline: 1.2493x; 1.2493x over previous
//
#include <hip/hip_runtime.h>
#include <stdint.h>

#define EPSF 1e-6f

typedef unsigned short u16;
typedef __attribute__((ext_vector_type(8))) short short8;
typedef __attribute__((ext_vector_type(4))) float f32x4;

__device__ __forceinline__ float us2f(u16 u) {
  union { float f; unsigned int i; } c; c.i = ((unsigned int)u) << 16; return c.f;
}
__device__ __forceinline__ u16 f2bfu(float f) {
  union { float f; unsigned int i; } c; c.f = f;
  unsigned int i = c.i;
  return (u16)((i + 0x7FFFu + ((i >> 16) & 1u)) >> 16);
}
__device__ __forceinline__ float sigm(float x) { return 1.f / (1.f + __expf(-x)); }

typedef __attribute__((address_space(3))) unsigned int lds_u32;
typedef const __attribute__((address_space(1))) unsigned int glb_u32;
__device__ __forceinline__ void gl_lds16(const u16* g, u16* l) {
  __builtin_amdgcn_global_load_lds((glb_u32*)g, (lds_u32*)l, 16, 0, 0);
}

// ---------------- convert x (f32 -> bf16), 4 elems/thread ----------------
__global__ void k_cvt_x(const float* __restrict__ in, u16* __restrict__ out) {
  const int i = blockIdx.x * 256 + threadIdx.x;
  float4 v = ((const float4*)in)[i];
  ushort4 o;
  o.x = f2bfu(v.x); o.y = f2bfu(v.y); o.z = f2bfu(v.z); o.w = f2bfu(v.w);
  ((ushort4*)out)[i] = o;
}

// ---------------- transpose + convert: in f32 [R][C] -> out bf16 [C][R] ----------------
__global__ void k_transpose(const float* __restrict__ in, u16* __restrict__ out, int R, int C) {
  __shared__ float tile[32][33];
  const int tx = threadIdx.x & 31, ty = threadIdx.x >> 5;  // 32x8
  const int c0 = blockIdx.x << 5, r0 = blockIdx.y << 5;
  for (int i = ty; i < 32; i += 8) tile[i][tx] = in[(size_t)(r0 + i) * C + c0 + tx];
  __syncthreads();
  for (int i = ty; i < 32; i += 8) out[(size_t)(c0 + i) * R + r0 + tx] = f2bfu(tile[tx][i]);
}

// ---------------- GEMM: A[M][768] bf16 x BT[NC][768] bf16, 128x128 tile, BK=32 ----------------
template <int MODE>
__global__ __launch_bounds__(256) void k_gemm(
    const u16* __restrict__ A, const u16* __restrict__ BT,
    const float* __restrict__ bias,
    u16* __restrict__ qo, u16* __restrict__ ko, u16* __restrict__ vo,
    float* __restrict__ outf)
{
  __shared__ __align__(16) u16 sA[2][128 * 32];
  __shared__ __align__(16) u16 sB[2][128 * 32];
  const int tid = threadIdx.x;
  const int lane = tid & 63;
  const int wid = tid >> 6;
  const int wr = wid >> 1, wc = wid & 1;
  // bijective XCD swizzle (nwg % 8 == 0 for both grids)
  const int nx = gridDim.x;
  int lid = blockIdx.y * nx + blockIdx.x;
  const int q8 = (nx * gridDim.y) >> 3;
  lid = (lid & 7) * q8 + (lid >> 3);
  const int m0 = (lid / nx) << 7;
  const int n0 = (lid % nx) << 7;
  const int srow = lane >> 2;          // 0..15 (row within 16-row chunk)
  const int skb = (lane & 3) << 3;     // 0,8,16,24 (k elems)

  const u16* ga0 = A  + (size_t)(m0 + (wid << 4) + srow) * 768 + skb;
  const u16* ga1 = A  + (size_t)(m0 + ((wid + 4) << 4) + srow) * 768 + skb;
  const u16* gb0 = BT + (size_t)(n0 + (wid << 4) + srow) * 768 + skb;
  const u16* gb1 = BT + (size_t)(n0 + ((wid + 4) << 4) + srow) * 768 + skb;

  f32x4 acc[4][4];
#pragma unroll
  for (int i = 0; i < 4; ++i)
#pragma unroll
    for (int j = 0; j < 4; ++j) acc[i][j] = (f32x4){0.f, 0.f, 0.f, 0.f};

#define STAGE(buf, ktel)                                        \
  do {                                                          \
    gl_lds16(ga0 + (ktel), &sA[buf][(wid) * 512]);              \
    gl_lds16(ga1 + (ktel), &sA[buf][(wid + 4) * 512]);          \
    gl_lds16(gb0 + (ktel), &sB[buf][(wid) * 512]);              \
    gl_lds16(gb1 + (ktel), &sB[buf][(wid + 4) * 512]);          \
  } while (0)

  STAGE(0, 0);
  asm volatile("s_waitcnt vmcnt(0)" ::: "memory");
  __syncthreads();

  const int r16 = lane & 15;
  const int kg8 = (lane >> 4) << 3;
  int cur = 0;
  for (int kt = 1; kt <= 24; ++kt) {
    if (kt < 24) {
      if (cur) STAGE(0, kt * 32); else STAGE(1, kt * 32);
    }
    const u16* pa = &sA[cur][0];
    const u16* pb = &sB[cur][0];
    short8 af[4], bfv[4];
#pragma unroll
    for (int i = 0; i < 4; ++i)
      af[i] = *(const short8*)(pa + ((wr << 6) + (i << 4) + r16) * 32 + kg8);
#pragma unroll
    for (int j = 0; j < 4; ++j)
      bfv[j] = *(const short8*)(pb + ((wc << 6) + (j << 4) + r16) * 32 + kg8);
#pragma unroll
    for (int i = 0; i < 4; ++i)
#pragma unroll
      for (int j = 0; j < 4; ++j)
        acc[i][j] = __builtin_amdgcn_mfma_f32_16x16x32_bf16(af[i], bfv[j], acc[i][j], 0, 0, 0);
    asm volatile("s_waitcnt vmcnt(0)" ::: "memory");
    __syncthreads();
    cur ^= 1;
  }
#undef STAGE

#pragma unroll
  for (int i = 0; i < 4; ++i) {
    const int rowb = m0 + (wr << 6) + (i << 4) + ((lane >> 4) << 2);
#pragma unroll
    for (int j = 0; j < 4; ++j) {
      const int col = n0 + (wc << 6) + (j << 4) + r16;
      const float bcol = bias[col];
      if (MODE == 0) {
        const int s = (col >= 1536) ? 2 : ((col >= 768) ? 1 : 0);
        const int cr = col - s * 768;
        const int h = cr >> 6, d = cr & 63;
        u16* dst = (s == 0) ? qo : ((s == 1) ? ko : vo);
#pragma unroll
        for (int rg = 0; rg < 4; ++rg) {
          const int row = rowb + rg;
          const int b = row >> 12, n = row & 4095;
          float val = acc[i][j][rg] + bcol;
          if (s < 2) val = sigm(val);
          dst[(((size_t)(b * 12 + h) << 12) + n) * 64 + d] = f2bfu(val);
        }
      } else {
#pragma unroll
        for (int rg = 0; rg < 4; ++rg) {
          const int row = rowb + rg;
          outf[(size_t)row * 768 + col] = sigm(2.f * (acc[i][j][rg] + bcol));
        }
      }
    }
  }
}

// ---------------- qsum/ksum over N: coalesced 16B loads, LDS reduce, atomics ----------------
__global__ __launch_bounds__(256) void k_sums(const u16* __restrict__ q, const u16* __restrict__ k,
                                              float* __restrict__ qsum, float* __restrict__ ksum) {
  const int bh = blockIdx.x >> 3, sp = blockIdx.x & 7;
  const int tid = threadIdx.x;
  const int d8 = (tid & 7) << 3, nl = tid >> 3;  // 8 d-groups x 32 n-lanes
  const u16* qb = q + ((size_t)bh << 18);
  const u16* kb = k + ((size_t)bh << 18);
  float sq[8], sk[8];
#pragma unroll
  for (int u = 0; u < 8; ++u) { sq[u] = 0.f; sk[u] = 0.f; }
  for (int it = 0; it < 16; ++it) {
    const int n = (sp << 9) + (it << 5) + nl;
    short8 a = *(const short8*)(qb + ((size_t)n << 6) + d8);
    short8 b = *(const short8*)(kb + ((size_t)n << 6) + d8);
#pragma unroll
    for (int u = 0; u < 8; ++u) { sq[u] += us2f((u16)a[u]); sk[u] += us2f((u16)b[u]); }
  }
  __shared__ float rq[32][68];
  __shared__ float rk[32][68];
#pragma unroll
  for (int u = 0; u < 8; ++u) { rq[nl][d8 + u] = sq[u]; rk[nl][d8 + u] = sk[u]; }
  __syncthreads();
  if (tid < 128) {
    const int which = tid >> 6, d = tid & 63;
    float s = 0.f;
    if (which == 0) {
#pragma unroll
      for (int g = 0; g < 32; ++g) s += rq[g][d];
      atomicAdd(&qsum[(bh << 6) + d], s);
    } else {
#pragma unroll
      for (int g = 0; g < 32; ++g) s += rk[g][d];
      atomicAdd(&ksum[(bh << 6) + d], s);
    }
  }
}

// ---------------- si/so + qsi/kso ----------------
__global__ __launch_bounds__(256) void k_flow1(
    const u16* __restrict__ q, const u16* __restrict__ k,
    const float* __restrict__ qsum, const float* __restrict__ ksum,
    float* __restrict__ si_out, float* __restrict__ qsi, float* __restrict__ kso)
{
  const int bh = blockIdx.x >> 3, sp = blockIdx.x & 7;
  const int lane = threadIdx.x & 63, wid = threadIdx.x >> 6;
  const int j = lane & 15;
  const int grp = (wid << 2) | (lane >> 4);
  const u16* qb = q + ((size_t)bh << 18);
  const u16* kb = k + ((size_t)bh << 18);
  float ke[4], qe[4];
#pragma unroll
  for (int t = 0; t < 4; ++t) {
    ke[t] = ksum[(bh << 6) + (j << 2) + t] + EPSF;
    qe[t] = qsum[(bh << 6) + (j << 2) + t] + EPSF;
  }
  float Sk = ke[0] + ke[1] + ke[2] + ke[3];
  float Sq = qe[0] + qe[1] + qe[2] + qe[3];
#pragma unroll
  for (int msk = 1; msk < 16; msk <<= 1) { Sk += __shfl_xor(Sk, msk, 64); Sq += __shfl_xor(Sq, msk, 64); }
  const float cK = EPSF * Sk + EPSF;
  const float cQ = EPSF * Sq + EPSF;
  float aq0 = 0, aq1 = 0, aq2 = 0, aq3 = 0, ak0 = 0, ak1 = 0, ak2 = 0, ak3 = 0;
  const int nbase = sp << 9;
  for (int it = 0; it < 32; ++it) {
    const int n = nbase + (it << 4) + grp;
    const uint64_t lq = *(const uint64_t*)(qb + ((size_t)n << 6) + (j << 2));
    const uint64_t lk = *(const uint64_t*)(kb + ((size_t)n << 6) + (j << 2));
    const float q0 = us2f((u16)lq), q1 = us2f((u16)(lq >> 16)), q2 = us2f((u16)(lq >> 32)), q3 = us2f((u16)(lq >> 48));
    const float k0 = us2f((u16)lk), k1 = us2f((u16)(lk >> 16)), k2 = us2f((u16)(lk >> 32)), k3 = us2f((u16)(lk >> 48));
    float dq = q0 * ke[0] + q1 * ke[1] + q2 * ke[2] + q3 * ke[3];
    float dk = k0 * qe[0] + k1 * qe[1] + k2 * qe[2] + k3 * qe[3];
#pragma unroll
    for (int msk = 1; msk < 16; msk <<= 1) { dq += __shfl_xor(dq, msk, 64); dk += __shfl_xor(dk, msk, 64); }
    const float si = 1.f / (dq + cK);
    const float so = 1.f / (dk + cQ);
    if (j == 0) si_out[(bh << 12) + n] = si;
    aq0 += q0 * si; aq1 += q1 * si; aq2 += q2 * si; aq3 += q3 * si;
    ak0 += k0 * so; ak1 += k1 * so; ak2 += k2 * so; ak3 += k3 * so;
  }
  __shared__ float redq[16][64];
  __shared__ float redk[16][64];
  redq[grp][(j << 2) + 0] = aq0; redq[grp][(j << 2) + 1] = aq1;
  redq[grp][(j << 2) + 2] = aq2; redq[grp][(j << 2) + 3] = aq3;
  redk[grp][(j << 2) + 0] = ak0; redk[grp][(j << 2) + 1] = ak1;
  redk[grp][(j << 2) + 2] = ak2; redk[grp][(j << 2) + 3] = ak3;
  __syncthreads();
  if (threadIdx.x < 64) {
    float s1 = 0.f, s2 = 0.f;
#pragma unroll
    for (int g = 0; g < 16; ++g) { s1 += redq[g][threadIdx.x]; s2 += redk[g][threadIdx.x]; }
    atomicAdd(&qsi[(bh << 6) + threadIdx.x], s1);
    atomicAdd(&kso[(bh << 6) + threadIdx.x], s2);
  }
}

// ---------------- conserved sink/source -> m = si*sigmoid(cs); e = exp(clip(csrc)); sumexp ----------------
__global__ __launch_bounds__(256) void k_flow2(
    const u16* __restrict__ q, const u16* __restrict__ k,
    const float* __restrict__ qsi, const float* __restrict__ kso,
    const float* __restrict__ si_in,
    float* __restrict__ mo, float* __restrict__ eo, float* __restrict__ sumexp)
{
  const int bh = blockIdx.x >> 3, sp = blockIdx.x & 7;
  const int lane = threadIdx.x & 63, wid = threadIdx.x >> 6;
  const int j = lane & 15;
  const int grp = (wid << 2) | (lane >> 4);
  const u16* qb = q + ((size_t)bh << 18);
  const u16* kb = k + ((size_t)bh << 18);
  float soe[4], qie[4];
#pragma unroll
  for (int t = 0; t < 4; ++t) {
    soe[t] = kso[(bh << 6) + (j << 2) + t] + EPSF;
    qie[t] = qsi[(bh << 6) + (j << 2) + t] + EPSF;
  }
  float Ss = soe[0] + soe[1] + soe[2] + soe[3];
  float Si = qie[0] + qie[1] + qie[2] + qie[3];
#pragma unroll
  for (int msk = 1; msk < 16; msk <<= 1) { Ss += __shfl_xor(Ss, msk, 64); Si += __shfl_xor(Si, msk, 64); }
  const float cS = EPSF * Ss + EPSF;
  const float cR = EPSF * Si + EPSF;
  float esum = 0.f;
  const int nbase = sp << 9;
  for (int it = 0; it < 32; ++it) {
    const int n = nbase + (it << 4) + grp;
    const uint64_t lq = *(const uint64_t*)(qb + ((size_t)n << 6) + (j << 2));
    const uint64_t lk = *(const uint64_t*)(kb + ((size_t)n << 6) + (j << 2));
    const float q0 = us2f((u16)lq), q1 = us2f((u16)(lq >> 16)), q2 = us2f((u16)(lq >> 32)), q3 = us2f((u16)(lq >> 48));
    const float k0 = us2f((u16)lk), k1 = us2f((u16)(lk >> 16)), k2 = us2f((u16)(lk >> 32)), k3 = us2f((u16)(lk >> 48));
    float cs = q0 * soe[0] + q1 * soe[1] + q2 * soe[2] + q3 * soe[3];
    float cr = k0 * qie[0] + k1 * qie[1] + k2 * qie[2] + k3 * qie[3];
#pragma unroll
    for (int msk = 1; msk < 16; msk <<= 1) { cs += __shfl_xor(cs, msk, 64); cr += __shfl_xor(cr, msk, 64); }
    cs += cS;
    cr += cR;
    cr = fminf(1.f, fmaxf(-1.f, cr));
    const float ev = __expf(cr);
    if (j == 0) {
      const float sa = sigm(cs);
      mo[(bh << 12) + n] = si_in[(bh << 12) + n] * sa;
      eo[(bh << 12) + n] = ev;
      esum += ev;
    }
  }
  __shared__ float red[16];
  if (j == 0) red[grp] = esum;
  __syncthreads();
  if (threadIdx.x == 0) {
    float s = 0.f;
#pragma unroll
    for (int g = 0; g < 16; ++g) s += red[g];
    atomicAdd(&sumexp[bh], s);
  }
}

// ---------------- kv via MFMA: kvm[d][e] = sum_n (k[n,d]*e[n]) * v[n,e] ----------------
// Transpose-on-write staging into [64 d][136 n] rows; fragments are plain
// ds_read_b128 rows (same verified pattern as k_gemm). XOR column swizzle
// keyed on (d>>3)&7 makes the scalar scatter writes bank-conflict-free.
__global__ __launch_bounds__(256) void k_kv(
    const u16* __restrict__ k, const u16* __restrict__ v,
    const float* __restrict__ e_arr, float* __restrict__ kvm)
{
  __shared__ __align__(16) u16 smem[2 * 64 * 136];  // 34816 B; reused as f32 reduce buf
  u16* kT = smem;
  u16* vT = smem + 64 * 136;
  const int tid = threadIdx.x;
  const int bh = blockIdx.x >> 3, sp = blockIdx.x & 7;
  const int lane = tid & 63, wid = tid >> 6;
  const int r16 = lane & 15, g = lane >> 4;
  const u16* kb = k + ((size_t)bh << 18);
  const u16* vb = v + ((size_t)bh << 18);
  const float* eb = e_arr + ((size_t)bh << 12);

  f32x4 acc[4][4];
#pragma unroll
  for (int i = 0; i < 4; ++i)
#pragma unroll
    for (int j = 0; j < 4; ++j) acc[i][j] = (f32x4){0.f, 0.f, 0.f, 0.f};

  const int nf = (wid << 5) + (g << 3);  // wave n-window + lane-group k offset

  for (int st = 0; st < 4; ++st) {
    const int nst = (sp << 9) + (st << 7);
#pragma unroll
    for (int i = 0; i < 4; ++i) {
      const int c = tid + (i << 8);
      const int nl = c >> 3;              // 0..127
      const int d0 = (c & 7) << 3;        // 0..56
      const int ng = nst + nl;
      short8 k8 = *(const short8*)(kb + ((size_t)ng << 6) + d0);
      short8 v8 = *(const short8*)(vb + ((size_t)ng << 6) + d0);
      const float en = eb[ng];
      const int col = nl ^ (d0 & 56);     // XOR key ((d0>>3)&7)<<3 == d0&56
#pragma unroll
      for (int u = 0; u < 8; ++u) {
        kT[(d0 + u) * 136 + col] = f2bfu(us2f((u16)k8[u]) * en);
        vT[(d0 + u) * 136 + col] = (u16)(unsigned short)v8[u];
      }
    }
    __syncthreads();

    short8 af[4], bf[4];
#pragma unroll
    for (int mi = 0; mi < 4; ++mi) {
      const int row = (mi << 4) + r16;
      af[mi] = *(const short8*)&kT[row * 136 + (nf ^ (row & 56))];
    }
#pragma unroll
    for (int nj = 0; nj < 4; ++nj) {
      const int row = (nj << 4) + r16;
      bf[nj] = *(const short8*)&vT[row * 136 + (nf ^ (row & 56))];
    }
#pragma unroll
    for (int mi = 0; mi < 4; ++mi)
#pragma unroll
      for (int nj = 0; nj < 4; ++nj)
        acc[mi][nj] = __builtin_amdgcn_mfma_f32_16x16x32_bf16(af[mi], bf[nj], acc[mi][nj], 0, 0, 0);
    __syncthreads();
  }

  // cross-wave reduce (two 32-d halves through LDS) + coalesced atomics
  float* red = (float*)smem;
  float* kvb = kvm + ((size_t)bh << 12);
#pragma unroll
  for (int half = 0; half < 2; ++half) {
#pragma unroll
    for (int m2 = 0; m2 < 2; ++m2) {
      const int mi = (half << 1) + m2;
#pragma unroll
      for (int nj = 0; nj < 4; ++nj)
#pragma unroll
        for (int rg = 0; rg < 4; ++rg)
          red[(wid << 11) + (((m2 << 4) + (g << 2) + rg) << 6) + (nj << 4) + r16] = acc[mi][nj][rg];
    }
    __syncthreads();
    const int base = tid << 3;
#pragma unroll
    for (int u2 = 0; u2 < 2; ++u2) {
      const int o = base + (u2 << 2);
      float4 s0 = *(const float4*)&red[o];
      float4 s1 = *(const float4*)&red[2048 + o];
      float4 s2 = *(const float4*)&red[4096 + o];
      float4 s3 = *(const float4*)&red[6144 + o];
      s0.x += s1.x + s2.x + s3.x;
      s0.y += s1.y + s2.y + s3.y;
      s0.z += s1.z + s2.z + s3.z;
      s0.w += s1.w + s2.w + s3.w;
      const int gi = (half << 11) + o;
      atomicAdd(&kvb[gi + 0], s0.x);
      atomicAdd(&kvb[gi + 1], s0.y);
      atomicAdd(&kvb[gi + 2], s0.z);
      atomicAdd(&kvb[gi + 3], s0.w);
    }
    __syncthreads();
  }
}

// ---------------- x_update = (q @ kv) * m[n] * scale -> attn [B][N][C] bf16 (MFMA) ----------------
__global__ __launch_bounds__(256) void k_xup(
    const u16* __restrict__ q, const float* __restrict__ kvm,
    const float* __restrict__ m_arr, const float* __restrict__ sumexp,
    u16* __restrict__ attn)
{
  const int bh = blockIdx.y;
  const int n0 = blockIdx.x << 7;
  const int b = bh / 12, h = bh % 12;
  __shared__ __align__(16) u16 qs[128 * 72];   // stride 72 elems (144B): 2-way banks, 16B aligned
  __shared__ __align__(16) u16 kvs[64 * 72];   // kv^T as [e][d] bf16
  const int tid = threadIdx.x, lane = tid & 63, wid = tid >> 6;
  const u16* qg = q + ((size_t)bh << 18) + ((size_t)n0 << 6);
#pragma unroll
  for (int i = 0; i < 4; ++i) {
    const int c = tid + (i << 8);
    const int nl = c >> 3, d0 = (c & 7) << 3;
    *(short8*)&qs[nl * 72 + d0] = *(const short8*)(qg + (nl << 6) + d0);
  }
  const float* kvg = kvm + ((size_t)bh << 12);
#pragma unroll
  for (int i = 0; i < 4; ++i) {
    const int idx = (tid << 2) + (i << 10);
    const int d = idx >> 6, e0 = idx & 63;
    float4 vv = *(const float4*)(kvg + idx);
    kvs[(e0 + 0) * 72 + d] = f2bfu(vv.x);
    kvs[(e0 + 1) * 72 + d] = f2bfu(vv.y);
    kvs[(e0 + 2) * 72 + d] = f2bfu(vv.z);
    kvs[(e0 + 3) * 72 + d] = f2bfu(vv.w);
  }
  __syncthreads();
  const float scale = 4096.f / sumexp[bh];
  const int r16 = lane & 15, kg8 = (lane >> 4) << 3;
  f32x4 acc[2][4];
#pragma unroll
  for (int i = 0; i < 2; ++i)
#pragma unroll
    for (int j = 0; j < 4; ++j) acc[i][j] = (f32x4){0.f, 0.f, 0.f, 0.f};
#pragma unroll
  for (int kk = 0; kk < 2; ++kk) {
    short8 af[2], bfv[4];
#pragma unroll
    for (int mi = 0; mi < 2; ++mi)
      af[mi] = *(const short8*)&qs[((wid << 5) + (mi << 4) + r16) * 72 + (kk << 5) + kg8];
#pragma unroll
    for (int nj = 0; nj < 4; ++nj)
      bfv[nj] = *(const short8*)&kvs[((nj << 4) + r16) * 72 + (kk << 5) + kg8];
#pragma unroll
    for (int mi = 0; mi < 2; ++mi)
#pragma unroll
      for (int nj = 0; nj < 4; ++nj)
        acc[mi][nj] = __builtin_amdgcn_mfma_f32_16x16x32_bf16(af[mi], bfv[nj], acc[mi][nj], 0, 0, 0);
  }
#pragma unroll
  for (int mi = 0; mi < 2; ++mi) {
#pragma unroll
    for (int rg = 0; rg < 4; ++rg) {
      const int n = n0 + (wid << 5) + (mi << 4) + ((lane >> 4) << 2) + rg;
      const float mult = m_arr[((size_t)bh << 12) + n] * scale;
#pragma unroll
      for (int nj = 0; nj < 4; ++nj) {
        const int e = (nj << 4) + r16;
        attn[((size_t)(b * 4096 + n)) * 768 + (h << 6) + e] = f2bfu(acc[mi][nj][rg] * mult);
      }
    }
  }
}

extern "C" void kernel_launch(void* const* d_in, const int* in_sizes, int n_in,
                              void* d_out, int out_size, void* d_ws, size_t ws_size,
                              hipStream_t stream)
{
  (void)in_sizes; (void)n_in; (void)out_size; (void)ws_size;
  const float* x     = (const float*)d_in[0];
  const float* Wqkv  = (const float*)d_in[1];
  const float* bqkv  = (const float*)d_in[2];
  const float* Wproj = (const float*)d_in[3];
  const float* bproj = (const float*)d_in[4];
  float* out = (float*)d_out;

  char* ws = (char*)d_ws;
  size_t off = 0;
  auto alloc = [&](size_t bytes) -> char* {
    char* p = ws + off;
    off += (bytes + 255) & ~(size_t)255;
    return p;
  };
  u16* q    = (u16*)alloc(50331648);       // [B,H,N,D] bf16
  u16* k    = (u16*)alloc(50331648);
  u16* v    = (u16*)alloc(50331648);
  u16* xbf  = (u16*)alloc(50331648);       // x bf16; reused as attn output
  u16* WqT  = (u16*)alloc(3538944);        // [2304][768] bf16
  u16* WpT  = (u16*)alloc(1179648);        // [768][768] bf16
  float* si = (float*)alloc(1572864);      // [B*H][N]
  float* mb = (float*)alloc(1572864);      // si * sink_allocation
  float* eb = (float*)alloc(1572864);      // exp(clipped conserved_source)
  char* zbase = ws + off;
  float* qsum   = (float*)alloc(24576);
  float* ksum   = (float*)alloc(24576);
  float* qsi    = (float*)alloc(24576);
  float* kso    = (float*)alloc(24576);
  float* sumexp = (float*)alloc(512);
  float* kvm    = (float*)alloc(1572864);  // [B*H][64 d][64 e] f32
  const size_t zbytes = (size_t)((ws + off) - zbase);

  hipMemsetAsync(zbase, 0, zbytes, stream);
  k_cvt_x<<<24576, 256, 0, stream>>>(x, xbf);
  k_transpose<<<dim3(72, 24), 256, 0, stream>>>(Wqkv, WqT, 768, 2304);
  k_transpose<<<dim3(24, 24), 256, 0, stream>>>(Wproj, WpT, 768, 768);
  k_gemm<0><<<dim3(18, 256), 256, 0, stream>>>(xbf, WqT, bqkv, q, k, v, nullptr);
  k_sums<<<768, 256, 0, stream>>>(q, k, qsum, ksum);
  k_flow1<<<768, 256, 0, stream>>>(q, k, qsum, ksum, si, qsi, kso);
  k_flow2<<<768, 256, 0, stream>>>(q, k, qsi, kso, si, mb, eb, sumexp);
  k_kv<<<768, 256, 0, stream>>>(k, v, eb, kvm);
  k_xup<<<dim3(32, 96), 256, 0, stream>>>(q, kvm, mb, sumexp, xbf);
  k_gemm<1><<<dim3(6, 256), 256, 0, stream>>>(xbf, WpT, bproj, nullptr, nullptr, nullptr, out);
}